// Round 1
// baseline (254.447 us; speedup 1.0000x reference)
//
#include <hip/hip_runtime.h>

// Problem constants (from reference: img_feats (8, 2048, 256) fp32)
#define BATCH 8
#define SEQ   2048
#define DIM   256
#define TINV  10.0f   // 1 / TEMPERATURE
#define NEGW  10      // NEG_WINDOW

// GEMM tiling
#define BM 128
#define BN 128
#define BK 64
#define NTILE (SEQ / BM)                  // 16
#define NPAIR (NTILE * (NTILE + 1) / 2)   // 136 (ti <= tj)

typedef float f32x4  __attribute__((ext_vector_type(4)));
typedef short bf16x8 __attribute__((ext_vector_type(8)));

// float -> bf16 (round-to-nearest-even), bf16 bits -> float
__device__ __forceinline__ unsigned short f2b(float f) {
  union { float f; unsigned u; } v; v.f = f;
  unsigned r = v.u + 0x7fffu + ((v.u >> 16) & 1u);
  return (unsigned short)(r >> 16);
}
__device__ __forceinline__ float b2f(unsigned short u) {
  union { unsigned u; float f; } v; v.u = ((unsigned)u) << 16;
  return v.f;
}

// ---------------------------------------------------------------------------
// Kernel 1: L2-normalize rows (fp32 in) -> bf16 normalized rows in workspace.
// 4 rows per 256-thread block; one wave (64 lanes x float4) per row.
// ---------------------------------------------------------------------------
__global__ void normalize_bf16_kernel(const float* __restrict__ x,
                                      unsigned short* __restrict__ xb) {
  int row  = blockIdx.x * 4 + (threadIdx.x >> 6);
  int lane = threadIdx.x & 63;
  const float4 v = reinterpret_cast<const float4*>(x + (size_t)row * DIM)[lane];
  float ss = v.x * v.x + v.y * v.y + v.z * v.z + v.w * v.w;
#pragma unroll
  for (int off = 32; off; off >>= 1) ss += __shfl_xor(ss, off, 64);
  float rn = 1.0f / fmaxf(sqrtf(ss), 1e-12f);
  ushort4 o;
  o.x = f2b(v.x * rn); o.y = f2b(v.y * rn);
  o.z = f2b(v.z * rn); o.w = f2b(v.w * rn);
  reinterpret_cast<ushort4*>(xb + (size_t)row * DIM)[lane] = o;
}

// ---------------------------------------------------------------------------
// Kernel 2: per-batch Gram tiles (only ti<=tj, symmetry), bf16 MFMA 16x16x32.
// Fused epilogue: e = exp(10*cos) masked by |s-t|>=10, reduced to
// negsum[b,s] (rows) and, for off-diagonal tiles, negsum[b,t] (cols).
// LDS: [128 rows][8 x 16B slots] with XOR swizzle slot^=(row&7) -> no bank
// conflicts on ds_write_b128 or ds_read_b128.
// ---------------------------------------------------------------------------
__global__ __launch_bounds__(256, 2)
void sim_negsum_kernel(const unsigned short* __restrict__ xb,
                       float* __restrict__ negsum) {
  const int b = blockIdx.y;
  // map pair index -> (ti, tj) with ti <= tj
  int ti = 0, rem = blockIdx.x;
  while (rem >= NTILE - ti) { rem -= NTILE - ti; ti++; }
  const int tj = ti + rem;
  const bool diag = (ti == tj);
  const int s0 = ti * BM, t0 = tj * BN;

  __shared__ unsigned short Asm[BM * BK];   // 16 KB
  __shared__ unsigned short Bsm[BN * BK];   // 16 KB

  const unsigned short* Ag = xb + (size_t)b * SEQ * DIM + (size_t)s0 * DIM;
  const unsigned short* Bg = xb + (size_t)b * SEQ * DIM + (size_t)t0 * DIM;

  const int tid  = threadIdx.x;
  const int wid  = tid >> 6;
  const int lane = tid & 63;
  const int wm   = wid >> 1;       // wave row strip (0..1) -> rows wm*64..+64
  const int wn   = wid & 1;        // wave col strip (0..1)
  const int kg   = lane >> 4;      // k-group 0..3
  const int cl   = lane & 15;

  f32x4 acc[4][4];
#pragma unroll
  for (int m = 0; m < 4; ++m)
#pragma unroll
    for (int n = 0; n < 4; ++n)
      acc[m][n] = (f32x4){0.f, 0.f, 0.f, 0.f};

  for (int kt = 0; kt < DIM / BK; ++kt) {   // 4 K-steps
    // ---- stage A and B tiles (reg-staged, swizzled ds_write_b128) ----
#pragma unroll
    for (int i = 0; i < 4; ++i) {
      int c = i * 256 + tid;          // 16B chunk id, 0..1023
      int row = c >> 3, slot = c & 7; // 8 slots of 16B per 128B row
      const size_t goff = (size_t)row * DIM + kt * BK + slot * 8;
      uint4 va = *reinterpret_cast<const uint4*>(Ag + goff);
      uint4 vb = *reinterpret_cast<const uint4*>(Bg + goff);
      int loff = row * 128 + ((slot ^ (row & 7)) << 4);
      *reinterpret_cast<uint4*>(reinterpret_cast<char*>(Asm) + loff) = va;
      *reinterpret_cast<uint4*>(reinterpret_cast<char*>(Bsm) + loff) = vb;
    }
    __syncthreads();

    // ---- MFMA over 2 k-chunks of 32 ----
#pragma unroll
    for (int kk = 0; kk < BK / 32; ++kk) {
      bf16x8 af[4], bfr[4];
#pragma unroll
      for (int m = 0; m < 4; ++m) {
        int r = wm * 64 + m * 16 + cl;
        int slot = kk * 4 + kg;
        af[m] = *reinterpret_cast<const bf16x8*>(
            reinterpret_cast<const char*>(Asm) + r * 128 + ((slot ^ (r & 7)) << 4));
      }
#pragma unroll
      for (int n = 0; n < 4; ++n) {
        int r = wn * 64 + n * 16 + cl;
        int slot = kk * 4 + kg;
        bfr[n] = *reinterpret_cast<const bf16x8*>(
            reinterpret_cast<const char*>(Bsm) + r * 128 + ((slot ^ (r & 7)) << 4));
      }
#pragma unroll
      for (int m = 0; m < 4; ++m)
#pragma unroll
        for (int n = 0; n < 4; ++n)
          acc[m][n] = __builtin_amdgcn_mfma_f32_16x16x32_bf16(
              af[m], bfr[n], acc[m][n], 0, 0, 0);
    }
    __syncthreads();
  }

  // ---- epilogue: exp + mask + row/col partial sums ----
  // C/D layout (HW-verified): col = lane&15, row = (lane>>4)*4 + reg
  float rowpart[4][4];   // [m][reg]
  float colpart[4];      // [n]
#pragma unroll
  for (int m = 0; m < 4; ++m)
#pragma unroll
    for (int r = 0; r < 4; ++r) rowpart[m][r] = 0.f;
#pragma unroll
  for (int n = 0; n < 4; ++n) colpart[n] = 0.f;

#pragma unroll
  for (int m = 0; m < 4; ++m) {
#pragma unroll
    for (int n = 0; n < 4; ++n) {
#pragma unroll
      for (int r = 0; r < 4; ++r) {
        int srow = s0 + wm * 64 + m * 16 + (kg << 2) + r;
        int tcol = t0 + wn * 64 + n * 16 + cl;
        int d = srow - tcol; d = d < 0 ? -d : d;
        float e = (d >= NEGW) ? __expf(acc[m][n][r] * TINV) : 0.f;
        rowpart[m][r] += e;
        colpart[n]    += e;
      }
    }
  }

  // row sums: reduce over the 16 lanes of each lane>>4 group (cols)
#pragma unroll
  for (int off = 1; off <= 8; off <<= 1)
#pragma unroll
    for (int m = 0; m < 4; ++m)
#pragma unroll
      for (int r = 0; r < 4; ++r)
        rowpart[m][r] += __shfl_xor(rowpart[m][r], off, 64);
  if (cl == 0) {
#pragma unroll
    for (int m = 0; m < 4; ++m)
#pragma unroll
      for (int r = 0; r < 4; ++r)
        atomicAdd(&negsum[(size_t)b * SEQ + s0 + wm * 64 + m * 16 + (kg << 2) + r],
                  rowpart[m][r]);
  }

  // col sums (only off-diagonal tiles: the mirrored ordered pairs (t,s))
  if (!diag) {
#pragma unroll
    for (int off = 16; off <= 32; off <<= 1)
#pragma unroll
      for (int n = 0; n < 4; ++n)
        colpart[n] += __shfl_xor(colpart[n], off, 64);
    if (lane < 16) {
#pragma unroll
      for (int n = 0; n < 4; ++n)
        atomicAdd(&negsum[(size_t)b * SEQ + t0 + wn * 64 + n * 16 + lane],
                  colpart[n]);
    }
  }
}

// ---------------------------------------------------------------------------
// Kernel 3: positive pairs (s, s+1). One wave per pair; dot over 256 dims,
// then both anchor terms: log(exp(sp) + negsum[anchor]) - sp.
// ---------------------------------------------------------------------------
__device__ __forceinline__ int negcnt(int s) {
  int a = s - (NEGW - 1);      if (a < 0) a = 0;
  int b = SEQ - NEGW - s;      if (b < 0) b = 0;
  return a + b;
}

__global__ void pos_loss_kernel(const unsigned short* __restrict__ xb,
                                const float* __restrict__ negsum,
                                float* __restrict__ loss) {
  int p = blockIdx.x * 4 + (threadIdx.x >> 6);   // pair id, exact grid
  int lane = threadIdx.x & 63;
  int b = p / (SEQ - 1), s = p % (SEQ - 1);
  const ushort4 u = reinterpret_cast<const ushort4*>(
      xb + ((size_t)b * SEQ + s) * DIM)[lane];
  const ushort4 w = reinterpret_cast<const ushort4*>(
      xb + ((size_t)b * SEQ + s + 1) * DIM)[lane];
  float dot = b2f(u.x) * b2f(w.x) + b2f(u.y) * b2f(w.y) +
              b2f(u.z) * b2f(w.z) + b2f(u.w) * b2f(w.w);
#pragma unroll
  for (int off = 32; off; off >>= 1) dot += __shfl_xor(dot, off, 64);
  if (lane == 0) {
    float sp = dot * TINV;
    float e = __expf(sp);
    float term = 0.f;
    if (negcnt(s) > 0)     term += logf(e + negsum[(size_t)b * SEQ + s])     - sp;
    if (negcnt(s + 1) > 0) term += logf(e + negsum[(size_t)b * SEQ + s + 1]) - sp;
    atomicAdd(loss, term);
  }
}

// ---------------------------------------------------------------------------
// Kernel 4: finalize — n_valid computed generically, out = loss / n_valid.
// ---------------------------------------------------------------------------
__global__ void finalize_kernel(const float* __restrict__ loss,
                                float* __restrict__ out) {
  int lane = threadIdx.x;   // 64 threads
  int cnt = 0;
  for (int s = lane; s < SEQ; s += 64) {
    if (negcnt(s) > 0) cnt += (s > 0) + (s < SEQ - 1);
  }
#pragma unroll
  for (int off = 32; off; off >>= 1) cnt += __shfl_xor(cnt, off, 64);
  if (lane == 0) {
    long long nv = (long long)BATCH * cnt;
    out[0] = (nv > 0) ? loss[0] / (float)nv : 0.0f;
  }
}

// ---------------------------------------------------------------------------
// Launch. Workspace layout (needs ~8.46 MB):
//   [0, 8388608)            xb: bf16 normalized feats
//   [8388608, +65536)       negsum: fp32 [B][S]
//   [8454144, +4)           loss accumulator
// ---------------------------------------------------------------------------
extern "C" void kernel_launch(void* const* d_in, const int* in_sizes, int n_in,
                              void* d_out, int out_size, void* d_ws, size_t ws_size,
                              hipStream_t stream) {
  const float* x = (const float*)d_in[0];
  unsigned short* xb = (unsigned short*)d_ws;
  const size_t XB_BYTES = (size_t)BATCH * SEQ * DIM * 2;   // 8388608
  const size_t NS_BYTES = (size_t)BATCH * SEQ * 4;         // 65536
  float* negsum = (float*)((char*)d_ws + XB_BYTES);
  float* loss   = (float*)((char*)d_ws + XB_BYTES + NS_BYTES);

  hipMemsetAsync((char*)d_ws + XB_BYTES, 0, NS_BYTES + 64, stream);

  normalize_bf16_kernel<<<(BATCH * SEQ) / 4, 256, 0, stream>>>(x, xb);

  dim3 g2(NPAIR, BATCH);
  sim_negsum_kernel<<<g2, 256, 0, stream>>>(xb, negsum);

  pos_loss_kernel<<<(BATCH * (SEQ - 1)) / 4, 256, 0, stream>>>(xb, negsum, loss);

  finalize_kernel<<<1, 64, 0, stream>>>(loss, (float*)d_out);
}

// Round 2
// 62.743 us; speedup vs baseline: 4.0554x; 4.0554x over previous
//
#include <hip/hip_runtime.h>

// Problem constants (from reference: img_feats (8, 2048, 256) fp32)
#define BATCH 8
#define SEQ   2048
#define DIM   256
#define TINV  10.0f   // 1 / TEMPERATURE
#define NEGW  10      // NEG_WINDOW

// GEMM tiling
#define BM 128
#define BN 128
#define BK 64
#define NTILE (SEQ / BM)                  // 16
#define NPAIR (NTILE * (NTILE + 1) / 2)   // 136 (ti <= tj)

typedef float f32x4  __attribute__((ext_vector_type(4)));
typedef short bf16x8 __attribute__((ext_vector_type(8)));

// float -> bf16 (round-to-nearest-even), bf16 bits -> float
__device__ __forceinline__ unsigned short f2b(float f) {
  union { float f; unsigned u; } v; v.f = f;
  unsigned r = v.u + 0x7fffu + ((v.u >> 16) & 1u);
  return (unsigned short)(r >> 16);
}
__device__ __forceinline__ float b2f(unsigned short u) {
  union { unsigned u; float f; } v; v.u = ((unsigned)u) << 16;
  return v.f;
}

// ---------------------------------------------------------------------------
// Kernel 1: L2-normalize rows (fp32 in) -> bf16 normalized rows in workspace.
// 4 rows per 256-thread block; one wave (64 lanes x float4) per row.
// ---------------------------------------------------------------------------
__global__ void normalize_bf16_kernel(const float* __restrict__ x,
                                      unsigned short* __restrict__ xb) {
  int row  = blockIdx.x * 4 + (threadIdx.x >> 6);
  int lane = threadIdx.x & 63;
  const float4 v = reinterpret_cast<const float4*>(x + (size_t)row * DIM)[lane];
  float ss = v.x * v.x + v.y * v.y + v.z * v.z + v.w * v.w;
#pragma unroll
  for (int off = 32; off; off >>= 1) ss += __shfl_xor(ss, off, 64);
  float rn = 1.0f / fmaxf(sqrtf(ss), 1e-12f);
  ushort4 o;
  o.x = f2b(v.x * rn); o.y = f2b(v.y * rn);
  o.z = f2b(v.z * rn); o.w = f2b(v.w * rn);
  reinterpret_cast<ushort4*>(xb + (size_t)row * DIM)[lane] = o;
}

// ---------------------------------------------------------------------------
// Kernel 2: per-batch Gram tiles (only ti<=tj, symmetry), bf16 MFMA 16x16x32.
// Fused epilogue: e = exp(10*cos) masked by |s-t|>=10, reduced to
// negsum[b,s] (rows) and, for off-diagonal tiles, negsum[b,t] (cols).
// LDS: [128 rows][8 x 16B slots] with XOR swizzle slot^=(row&7) -> no bank
// conflicts on ds_write_b128 or ds_read_b128.
// ---------------------------------------------------------------------------
__global__ __launch_bounds__(256, 2)
void sim_negsum_kernel(const unsigned short* __restrict__ xb,
                       float* __restrict__ negsum) {
  const int b = blockIdx.y;
  // map pair index -> (ti, tj) with ti <= tj
  int ti = 0, rem = blockIdx.x;
  while (rem >= NTILE - ti) { rem -= NTILE - ti; ti++; }
  const int tj = ti + rem;
  const bool diag = (ti == tj);
  const int s0 = ti * BM, t0 = tj * BN;

  __shared__ unsigned short Asm[BM * BK];   // 16 KB
  __shared__ unsigned short Bsm[BN * BK];   // 16 KB

  const unsigned short* Ag = xb + (size_t)b * SEQ * DIM + (size_t)s0 * DIM;
  const unsigned short* Bg = xb + (size_t)b * SEQ * DIM + (size_t)t0 * DIM;

  const int tid  = threadIdx.x;
  const int wid  = tid >> 6;
  const int lane = tid & 63;
  const int wm   = wid >> 1;       // wave row strip (0..1) -> rows wm*64..+64
  const int wn   = wid & 1;        // wave col strip (0..1)
  const int kg   = lane >> 4;      // k-group 0..3
  const int cl   = lane & 15;

  f32x4 acc[4][4];
#pragma unroll
  for (int m = 0; m < 4; ++m)
#pragma unroll
    for (int n = 0; n < 4; ++n)
      acc[m][n] = (f32x4){0.f, 0.f, 0.f, 0.f};

  for (int kt = 0; kt < DIM / BK; ++kt) {   // 4 K-steps
    // ---- stage A and B tiles (reg-staged, swizzled ds_write_b128) ----
#pragma unroll
    for (int i = 0; i < 4; ++i) {
      int c = i * 256 + tid;          // 16B chunk id, 0..1023
      int row = c >> 3, slot = c & 7; // 8 slots of 16B per 128B row
      const size_t goff = (size_t)row * DIM + kt * BK + slot * 8;
      uint4 va = *reinterpret_cast<const uint4*>(Ag + goff);
      uint4 vb = *reinterpret_cast<const uint4*>(Bg + goff);
      int loff = row * 128 + ((slot ^ (row & 7)) << 4);
      *reinterpret_cast<uint4*>(reinterpret_cast<char*>(Asm) + loff) = va;
      *reinterpret_cast<uint4*>(reinterpret_cast<char*>(Bsm) + loff) = vb;
    }
    __syncthreads();

    // ---- MFMA over 2 k-chunks of 32 ----
#pragma unroll
    for (int kk = 0; kk < BK / 32; ++kk) {
      bf16x8 af[4], bfr[4];
#pragma unroll
      for (int m = 0; m < 4; ++m) {
        int r = wm * 64 + m * 16 + cl;
        int slot = kk * 4 + kg;
        af[m] = *reinterpret_cast<const bf16x8*>(
            reinterpret_cast<const char*>(Asm) + r * 128 + ((slot ^ (r & 7)) << 4));
      }
#pragma unroll
      for (int n = 0; n < 4; ++n) {
        int r = wn * 64 + n * 16 + cl;
        int slot = kk * 4 + kg;
        bfr[n] = *reinterpret_cast<const bf16x8*>(
            reinterpret_cast<const char*>(Bsm) + r * 128 + ((slot ^ (r & 7)) << 4));
      }
#pragma unroll
      for (int m = 0; m < 4; ++m)
#pragma unroll
        for (int n = 0; n < 4; ++n)
          acc[m][n] = __builtin_amdgcn_mfma_f32_16x16x32_bf16(
              af[m], bfr[n], acc[m][n], 0, 0, 0);
    }
    __syncthreads();
  }

  // ---- epilogue: exp + mask + row/col partial sums ----
  // C/D layout (HW-verified): col = lane&15, row = (lane>>4)*4 + reg
  float rowpart[4][4];   // [m][reg]
  float colpart[4];      // [n]
#pragma unroll
  for (int m = 0; m < 4; ++m)
#pragma unroll
    for (int r = 0; r < 4; ++r) rowpart[m][r] = 0.f;
#pragma unroll
  for (int n = 0; n < 4; ++n) colpart[n] = 0.f;

#pragma unroll
  for (int m = 0; m < 4; ++m) {
#pragma unroll
    for (int n = 0; n < 4; ++n) {
#pragma unroll
      for (int r = 0; r < 4; ++r) {
        int srow = s0 + wm * 64 + m * 16 + (kg << 2) + r;
        int tcol = t0 + wn * 64 + n * 16 + cl;
        int d = srow - tcol; d = d < 0 ? -d : d;
        float e = (d >= NEGW) ? __expf(acc[m][n][r] * TINV) : 0.f;
        rowpart[m][r] += e;
        colpart[n]    += e;
      }
    }
  }

  // row sums: reduce over the 16 lanes of each lane>>4 group (cols)
#pragma unroll
  for (int off = 1; off <= 8; off <<= 1)
#pragma unroll
    for (int m = 0; m < 4; ++m)
#pragma unroll
      for (int r = 0; r < 4; ++r)
        rowpart[m][r] += __shfl_xor(rowpart[m][r], off, 64);
  if (cl == 0) {
#pragma unroll
    for (int m = 0; m < 4; ++m)
#pragma unroll
      for (int r = 0; r < 4; ++r)
        atomicAdd(&negsum[(size_t)b * SEQ + s0 + wm * 64 + m * 16 + (kg << 2) + r],
                  rowpart[m][r]);
  }

  // col sums (only off-diagonal tiles: the mirrored ordered pairs (t,s))
  if (!diag) {
#pragma unroll
    for (int off = 16; off <= 32; off <<= 1)
#pragma unroll
      for (int n = 0; n < 4; ++n)
        colpart[n] += __shfl_xor(colpart[n], off, 64);
    if (lane < 16) {
#pragma unroll
      for (int n = 0; n < 4; ++n)
        atomicAdd(&negsum[(size_t)b * SEQ + t0 + wn * 64 + n * 16 + lane],
                  colpart[n]);
    }
  }
}

// ---------------------------------------------------------------------------
// Kernel 3: positive pairs (s, s+1). Grid-strided waves, one wave per pair
// iteration; per-wave register accumulation; ONE atomic per block.
// (Round-1 fix: 16,376 same-address atomics serialized at ~13 ns each
//  = 210 us. Now 256 atomics total.)
// ---------------------------------------------------------------------------
#define POS_BLOCKS 256
#define POS_WAVES  (POS_BLOCKS * 4)

__device__ __forceinline__ int negcnt(int s) {
  int a = s - (NEGW - 1);      if (a < 0) a = 0;
  int b = SEQ - NEGW - s;      if (b < 0) b = 0;
  return a + b;
}

__global__ __launch_bounds__(256)
void pos_loss_kernel(const unsigned short* __restrict__ xb,
                     const float* __restrict__ negsum,
                     float* __restrict__ loss) {
  __shared__ float red[4];
  const int wid  = threadIdx.x >> 6;
  const int lane = threadIdx.x & 63;
  const int gw   = blockIdx.x * 4 + wid;   // global wave id
  const int NP   = BATCH * (SEQ - 1);

  float term = 0.f;
  for (int p = gw; p < NP; p += POS_WAVES) {
    int b = p / (SEQ - 1), s = p % (SEQ - 1);
    const ushort4 u = reinterpret_cast<const ushort4*>(
        xb + ((size_t)b * SEQ + s) * DIM)[lane];
    const ushort4 w = reinterpret_cast<const ushort4*>(
        xb + ((size_t)b * SEQ + s + 1) * DIM)[lane];
    float dot = b2f(u.x) * b2f(w.x) + b2f(u.y) * b2f(w.y) +
                b2f(u.z) * b2f(w.z) + b2f(u.w) * b2f(w.w);
#pragma unroll
    for (int off = 32; off; off >>= 1) dot += __shfl_xor(dot, off, 64);
    // all lanes hold the full dot after the butterfly; split the two log
    // terms across lanes 0 and 1 so they run in parallel.
    float sp = dot * TINV;
    float e  = __expf(sp);
    if (lane == 0 && negcnt(s) > 0)
      term += logf(e + negsum[(size_t)b * SEQ + s]) - sp;
    if (lane == 1 && negcnt(s + 1) > 0)
      term += logf(e + negsum[(size_t)b * SEQ + s + 1]) - sp;
  }
  // wave reduce (only lanes 0,1 carry nonzero, but butterfly is cheap)
#pragma unroll
  for (int off = 32; off; off >>= 1) term += __shfl_xor(term, off, 64);
  if (lane == 0) red[wid] = term;
  __syncthreads();
  if (threadIdx.x == 0)
    atomicAdd(loss, red[0] + red[1] + red[2] + red[3]);
}

// ---------------------------------------------------------------------------
// Kernel 4: finalize — n_valid computed generically, out = loss / n_valid.
// ---------------------------------------------------------------------------
__global__ void finalize_kernel(const float* __restrict__ loss,
                                float* __restrict__ out) {
  int lane = threadIdx.x;   // 64 threads
  int cnt = 0;
  for (int s = lane; s < SEQ; s += 64) {
    if (negcnt(s) > 0) cnt += (s > 0) + (s < SEQ - 1);
  }
#pragma unroll
  for (int off = 32; off; off >>= 1) cnt += __shfl_xor(cnt, off, 64);
  if (lane == 0) {
    long long nv = (long long)BATCH * cnt;
    out[0] = (nv > 0) ? loss[0] / (float)nv : 0.0f;
  }
}

// ---------------------------------------------------------------------------
// Launch. Workspace layout (needs ~8.46 MB):
//   [0, 8388608)            xb: bf16 normalized feats
//   [8388608, +65536)       negsum: fp32 [B][S]
//   [8454144, +4)           loss accumulator
// ---------------------------------------------------------------------------
extern "C" void kernel_launch(void* const* d_in, const int* in_sizes, int n_in,
                              void* d_out, int out_size, void* d_ws, size_t ws_size,
                              hipStream_t stream) {
  const float* x = (const float*)d_in[0];
  unsigned short* xb = (unsigned short*)d_ws;
  const size_t XB_BYTES = (size_t)BATCH * SEQ * DIM * 2;   // 8388608
  const size_t NS_BYTES = (size_t)BATCH * SEQ * 4;         // 65536
  float* negsum = (float*)((char*)d_ws + XB_BYTES);
  float* loss   = (float*)((char*)d_ws + XB_BYTES + NS_BYTES);

  hipMemsetAsync((char*)d_ws + XB_BYTES, 0, NS_BYTES + 64, stream);

  normalize_bf16_kernel<<<(BATCH * SEQ) / 4, 256, 0, stream>>>(x, xb);

  dim3 g2(NPAIR, BATCH);
  sim_negsum_kernel<<<g2, 256, 0, stream>>>(xb, negsum);

  pos_loss_kernel<<<POS_BLOCKS, 256, 0, stream>>>(xb, negsum, loss);

  finalize_kernel<<<1, 64, 0, stream>>>(loss, (float*)d_out);
}

// Round 3
// 57.830 us; speedup vs baseline: 4.3999x; 1.0850x over previous
//
#include <hip/hip_runtime.h>

// Problem constants (from reference: img_feats (8, 2048, 256) fp32)
#define BATCH 8
#define SEQ   2048
#define DIM   256
#define TINV  10.0f   // 1 / TEMPERATURE
#define NEGW  10      // NEG_WINDOW

// GEMM tiling
#define BM 128
#define BN 128
#define BK 64
#define NTILE (SEQ / BM)                  // 16
#define NPAIR (NTILE * (NTILE + 1) / 2)   // 136 (ti <= tj)

typedef float f32x4  __attribute__((ext_vector_type(4)));
typedef short bf16x8 __attribute__((ext_vector_type(8)));

// float -> bf16 (round-to-nearest-even), bf16 bits -> float
__device__ __forceinline__ unsigned short f2b(float f) {
  union { float f; unsigned u; } v; v.f = f;
  unsigned r = v.u + 0x7fffu + ((v.u >> 16) & 1u);
  return (unsigned short)(r >> 16);
}
__device__ __forceinline__ float b2f(unsigned short u) {
  union { unsigned u; float f; } v; v.u = ((unsigned)u) << 16;
  return v.f;
}

// ---------------------------------------------------------------------------
// Kernel 1: L2-normalize rows (fp32 in) -> bf16 normalized rows in workspace.
// 4 rows per 256-thread block; one wave (64 lanes x float4) per row.
// Round-2 fix: hipMemsetAsync's fillBuffer dispatch was 42 us of pure
// latency at the head of the chain — fold negsum/loss zero-init in here
// (blocks 0..64 write disjoint regions; consumers are later dispatches).
// ---------------------------------------------------------------------------
__global__ void normalize_bf16_kernel(const float* __restrict__ x,
                                      unsigned short* __restrict__ xb,
                                      float* __restrict__ zero_region) {
  if (blockIdx.x < 64) {
    // 64 blocks x 256 threads = 16384 floats = negsum[B][S]
    zero_region[blockIdx.x * 256 + threadIdx.x] = 0.f;
  } else if (blockIdx.x == 64 && threadIdx.x < 16) {
    zero_region[16384 + threadIdx.x] = 0.f;   // loss accumulator + pad
  }
  int row  = blockIdx.x * 4 + (threadIdx.x >> 6);
  int lane = threadIdx.x & 63;
  const float4 v = reinterpret_cast<const float4*>(x + (size_t)row * DIM)[lane];
  float ss = v.x * v.x + v.y * v.y + v.z * v.z + v.w * v.w;
#pragma unroll
  for (int off = 32; off; off >>= 1) ss += __shfl_xor(ss, off, 64);
  float rn = 1.0f / fmaxf(sqrtf(ss), 1e-12f);
  ushort4 o;
  o.x = f2b(v.x * rn); o.y = f2b(v.y * rn);
  o.z = f2b(v.z * rn); o.w = f2b(v.w * rn);
  reinterpret_cast<ushort4*>(xb + (size_t)row * DIM)[lane] = o;
}

// ---------------------------------------------------------------------------
// Kernel 2: per-batch Gram tiles (only ti<=tj, symmetry), bf16 MFMA 16x16x32.
// Fused epilogue: e = exp(10*cos) masked by |s-t|>=10, reduced to
// negsum[b,s] (rows) and, for off-diagonal tiles, negsum[b,t] (cols).
// LDS: [128 rows][8 x 16B slots] with XOR swizzle slot^=(row&7) -> no bank
// conflicts on ds_write_b128 or ds_read_b128.
// ---------------------------------------------------------------------------
__global__ __launch_bounds__(256, 2)
void sim_negsum_kernel(const unsigned short* __restrict__ xb,
                       float* __restrict__ negsum) {
  const int b = blockIdx.y;
  // map pair index -> (ti, tj) with ti <= tj
  int ti = 0, rem = blockIdx.x;
  while (rem >= NTILE - ti) { rem -= NTILE - ti; ti++; }
  const int tj = ti + rem;
  const bool diag = (ti == tj);
  const int s0 = ti * BM, t0 = tj * BN;

  __shared__ unsigned short Asm[BM * BK];   // 16 KB
  __shared__ unsigned short Bsm[BN * BK];   // 16 KB

  const unsigned short* Ag = xb + (size_t)b * SEQ * DIM + (size_t)s0 * DIM;
  const unsigned short* Bg = xb + (size_t)b * SEQ * DIM + (size_t)t0 * DIM;

  const int tid  = threadIdx.x;
  const int wid  = tid >> 6;
  const int lane = tid & 63;
  const int wm   = wid >> 1;       // wave row strip (0..1) -> rows wm*64..+64
  const int wn   = wid & 1;        // wave col strip (0..1)
  const int kg   = lane >> 4;      // k-group 0..3
  const int cl   = lane & 15;

  f32x4 acc[4][4];
#pragma unroll
  for (int m = 0; m < 4; ++m)
#pragma unroll
    for (int n = 0; n < 4; ++n)
      acc[m][n] = (f32x4){0.f, 0.f, 0.f, 0.f};

  for (int kt = 0; kt < DIM / BK; ++kt) {   // 4 K-steps
    // ---- stage A and B tiles (reg-staged, swizzled ds_write_b128) ----
#pragma unroll
    for (int i = 0; i < 4; ++i) {
      int c = i * 256 + tid;          // 16B chunk id, 0..1023
      int row = c >> 3, slot = c & 7; // 8 slots of 16B per 128B row
      const size_t goff = (size_t)row * DIM + kt * BK + slot * 8;
      uint4 va = *reinterpret_cast<const uint4*>(Ag + goff);
      uint4 vb = *reinterpret_cast<const uint4*>(Bg + goff);
      int loff = row * 128 + ((slot ^ (row & 7)) << 4);
      *reinterpret_cast<uint4*>(reinterpret_cast<char*>(Asm) + loff) = va;
      *reinterpret_cast<uint4*>(reinterpret_cast<char*>(Bsm) + loff) = vb;
    }
    __syncthreads();

    // ---- MFMA over 2 k-chunks of 32 ----
#pragma unroll
    for (int kk = 0; kk < BK / 32; ++kk) {
      bf16x8 af[4], bfr[4];
#pragma unroll
      for (int m = 0; m < 4; ++m) {
        int r = wm * 64 + m * 16 + cl;
        int slot = kk * 4 + kg;
        af[m] = *reinterpret_cast<const bf16x8*>(
            reinterpret_cast<const char*>(Asm) + r * 128 + ((slot ^ (r & 7)) << 4));
      }
#pragma unroll
      for (int n = 0; n < 4; ++n) {
        int r = wn * 64 + n * 16 + cl;
        int slot = kk * 4 + kg;
        bfr[n] = *reinterpret_cast<const bf16x8*>(
            reinterpret_cast<const char*>(Bsm) + r * 128 + ((slot ^ (r & 7)) << 4));
      }
#pragma unroll
      for (int m = 0; m < 4; ++m)
#pragma unroll
        for (int n = 0; n < 4; ++n)
          acc[m][n] = __builtin_amdgcn_mfma_f32_16x16x32_bf16(
              af[m], bfr[n], acc[m][n], 0, 0, 0);
    }
    __syncthreads();
  }

  // ---- epilogue: exp + mask + row/col partial sums ----
  // C/D layout (HW-verified): col = lane&15, row = (lane>>4)*4 + reg
  float rowpart[4][4];   // [m][reg]
  float colpart[4];      // [n]
#pragma unroll
  for (int m = 0; m < 4; ++m)
#pragma unroll
    for (int r = 0; r < 4; ++r) rowpart[m][r] = 0.f;
#pragma unroll
  for (int n = 0; n < 4; ++n) colpart[n] = 0.f;

#pragma unroll
  for (int m = 0; m < 4; ++m) {
#pragma unroll
    for (int n = 0; n < 4; ++n) {
#pragma unroll
      for (int r = 0; r < 4; ++r) {
        int srow = s0 + wm * 64 + m * 16 + (kg << 2) + r;
        int tcol = t0 + wn * 64 + n * 16 + cl;
        int d = srow - tcol; d = d < 0 ? -d : d;
        float e = (d >= NEGW) ? __expf(acc[m][n][r] * TINV) : 0.f;
        rowpart[m][r] += e;
        colpart[n]    += e;
      }
    }
  }

  // row sums: reduce over the 16 lanes of each lane>>4 group (cols)
#pragma unroll
  for (int off = 1; off <= 8; off <<= 1)
#pragma unroll
    for (int m = 0; m < 4; ++m)
#pragma unroll
      for (int r = 0; r < 4; ++r)
        rowpart[m][r] += __shfl_xor(rowpart[m][r], off, 64);
  if (cl == 0) {
#pragma unroll
    for (int m = 0; m < 4; ++m)
#pragma unroll
      for (int r = 0; r < 4; ++r)
        atomicAdd(&negsum[(size_t)b * SEQ + s0 + wm * 64 + m * 16 + (kg << 2) + r],
                  rowpart[m][r]);
  }

  // col sums (only off-diagonal tiles: the mirrored ordered pairs (t,s))
  if (!diag) {
#pragma unroll
    for (int off = 16; off <= 32; off <<= 1)
#pragma unroll
      for (int n = 0; n < 4; ++n)
        colpart[n] += __shfl_xor(colpart[n], off, 64);
    if (lane < 16) {
#pragma unroll
      for (int n = 0; n < 4; ++n)
        atomicAdd(&negsum[(size_t)b * SEQ + t0 + wn * 64 + n * 16 + lane],
                  colpart[n]);
    }
  }
}

// ---------------------------------------------------------------------------
// Kernel 3: positive pairs (s, s+1). Grid-strided waves, one wave per pair
// iteration; per-wave register accumulation; ONE atomic per block.
// ---------------------------------------------------------------------------
#define POS_BLOCKS 256
#define POS_WAVES  (POS_BLOCKS * 4)

__device__ __forceinline__ int negcnt(int s) {
  int a = s - (NEGW - 1);      if (a < 0) a = 0;
  int b = SEQ - NEGW - s;      if (b < 0) b = 0;
  return a + b;
}

__global__ __launch_bounds__(256)
void pos_loss_kernel(const unsigned short* __restrict__ xb,
                     const float* __restrict__ negsum,
                     float* __restrict__ loss) {
  __shared__ float red[4];
  const int wid  = threadIdx.x >> 6;
  const int lane = threadIdx.x & 63;
  const int gw   = blockIdx.x * 4 + wid;   // global wave id
  const int NP   = BATCH * (SEQ - 1);

  float term = 0.f;
  for (int p = gw; p < NP; p += POS_WAVES) {
    int b = p / (SEQ - 1), s = p % (SEQ - 1);
    const ushort4 u = reinterpret_cast<const ushort4*>(
        xb + ((size_t)b * SEQ + s) * DIM)[lane];
    const ushort4 w = reinterpret_cast<const ushort4*>(
        xb + ((size_t)b * SEQ + s + 1) * DIM)[lane];
    float dot = b2f(u.x) * b2f(w.x) + b2f(u.y) * b2f(w.y) +
                b2f(u.z) * b2f(w.z) + b2f(u.w) * b2f(w.w);
#pragma unroll
    for (int off = 32; off; off >>= 1) dot += __shfl_xor(dot, off, 64);
    // all lanes hold the full dot after the butterfly; split the two log
    // terms across lanes 0 and 1 so they run in parallel.
    float sp = dot * TINV;
    float e  = __expf(sp);
    if (lane == 0 && negcnt(s) > 0)
      term += logf(e + negsum[(size_t)b * SEQ + s]) - sp;
    if (lane == 1 && negcnt(s + 1) > 0)
      term += logf(e + negsum[(size_t)b * SEQ + s + 1]) - sp;
  }
  // wave reduce (only lanes 0,1 carry nonzero, but butterfly is cheap)
#pragma unroll
  for (int off = 32; off; off >>= 1) term += __shfl_xor(term, off, 64);
  if (lane == 0) red[wid] = term;
  __syncthreads();
  if (threadIdx.x == 0)
    atomicAdd(loss, red[0] + red[1] + red[2] + red[3]);
}

// ---------------------------------------------------------------------------
// Kernel 4: finalize — n_valid computed generically, out = loss / n_valid.
// ---------------------------------------------------------------------------
__global__ void finalize_kernel(const float* __restrict__ loss,
                                float* __restrict__ out) {
  int lane = threadIdx.x;   // 64 threads
  int cnt = 0;
  for (int s = lane; s < SEQ; s += 64) {
    if (negcnt(s) > 0) cnt += (s > 0) + (s < SEQ - 1);
  }
#pragma unroll
  for (int off = 32; off; off >>= 1) cnt += __shfl_xor(cnt, off, 64);
  if (lane == 0) {
    long long nv = (long long)BATCH * cnt;
    out[0] = (nv > 0) ? loss[0] / (float)nv : 0.0f;
  }
}

// ---------------------------------------------------------------------------
// Launch. Workspace layout (needs ~8.46 MB):
//   [0, 8388608)            xb: bf16 normalized feats
//   [8388608, +65536)       negsum: fp32 [B][S]
//   [8454144, +4)           loss accumulator
// ---------------------------------------------------------------------------
extern "C" void kernel_launch(void* const* d_in, const int* in_sizes, int n_in,
                              void* d_out, int out_size, void* d_ws, size_t ws_size,
                              hipStream_t stream) {
  const float* x = (const float*)d_in[0];
  unsigned short* xb = (unsigned short*)d_ws;
  const size_t XB_BYTES = (size_t)BATCH * SEQ * DIM * 2;   // 8388608
  const size_t NS_BYTES = (size_t)BATCH * SEQ * 4;         // 65536
  float* negsum = (float*)((char*)d_ws + XB_BYTES);
  float* loss   = (float*)((char*)d_ws + XB_BYTES + NS_BYTES);

  // zero-init of negsum+loss is folded into normalize_bf16_kernel
  normalize_bf16_kernel<<<(BATCH * SEQ) / 4, 256, 0, stream>>>(x, xb, negsum);

  dim3 g2(NPAIR, BATCH);
  sim_negsum_kernel<<<g2, 256, 0, stream>>>(xb, negsum);

  pos_loss_kernel<<<POS_BLOCKS, 256, 0, stream>>>(xb, negsum, loss);

  finalize_kernel<<<1, 64, 0, stream>>>(loss, (float*)d_out);
}

// Round 4
// 47.065 us; speedup vs baseline: 5.4062x; 1.2287x over previous
//
#include <hip/hip_runtime.h>

// Problem constants (from reference: img_feats (8, 2048, 256) fp32)
#define BATCH 8
#define SEQ   2048
#define DIM   256
#define TINV  10.0f   // 1 / TEMPERATURE
#define NEGW  10      // NEG_WINDOW

// GEMM tiling
#define BM 128
#define BN 128
#define BK 64
#define NTILE (SEQ / BM)                  // 16
#define NPAIR (NTILE * (NTILE + 1) / 2)   // 136 (ti <= tj)

typedef float f32x4  __attribute__((ext_vector_type(4)));
typedef short bf16x8 __attribute__((ext_vector_type(8)));

// float -> bf16 (round-to-nearest-even), bf16 bits -> float
__device__ __forceinline__ unsigned short f2b(float f) {
  union { float f; unsigned u; } v; v.f = f;
  unsigned r = v.u + 0x7fffu + ((v.u >> 16) & 1u);
  return (unsigned short)(r >> 16);
}
__device__ __forceinline__ float b2f(unsigned short u) {
  union { unsigned u; float f; } v; v.u = ((unsigned)u) << 16;
  return v.f;
}

// ---------------------------------------------------------------------------
// Kernel 1: L2-normalize rows (fp32 in) -> bf16 normalized rows in workspace.
// Also zero-inits negsum[B][S] + loss accumulator (blocks 0..64), replacing
// the 42us fillBuffer dispatch (round-2 lesson).
// ---------------------------------------------------------------------------
__global__ void normalize_bf16_kernel(const float* __restrict__ x,
                                      unsigned short* __restrict__ xb,
                                      float* __restrict__ zero_region) {
  if (blockIdx.x < 64) {
    zero_region[blockIdx.x * 256 + threadIdx.x] = 0.f;   // negsum
  } else if (blockIdx.x == 64 && threadIdx.x < 16) {
    zero_region[16384 + threadIdx.x] = 0.f;              // loss + pad
  }
  int row  = blockIdx.x * 4 + (threadIdx.x >> 6);
  int lane = threadIdx.x & 63;
  const float4 v = reinterpret_cast<const float4*>(x + (size_t)row * DIM)[lane];
  float ss = v.x * v.x + v.y * v.y + v.z * v.z + v.w * v.w;
#pragma unroll
  for (int off = 32; off; off >>= 1) ss += __shfl_xor(ss, off, 64);
  float rn = 1.0f / fmaxf(sqrtf(ss), 1e-12f);
  ushort4 o;
  o.x = f2b(v.x * rn); o.y = f2b(v.y * rn);
  o.z = f2b(v.z * rn); o.w = f2b(v.w * rn);
  reinterpret_cast<ushort4*>(xb + (size_t)row * DIM)[lane] = o;
}

// ---------------------------------------------------------------------------
// Kernel 2: per-batch Gram tiles (ti<=tj, symmetry), bf16 MFMA 16x16x32.
// Round-4: global_load_lds (width=16) staging with PRE-SWIZZLED global
// source (LDS dest linear as HW requires; the XOR swizzle is absorbed into
// each lane's global address, so the LDS image matches the round-3 passing
// kernel exactly). Double-buffered 2-phase prefetch: stage K(t+1) before
// MFMA(Kt); __syncthreads() supplies the vmcnt/lgkm drain.
// Epilogue: exp+mask -> negsum rows/cols, plus sp extraction for the
// adjacent positive pairs (each (s,s+1) lives in exactly one ti<=tj tile).
// ---------------------------------------------------------------------------
__device__ __forceinline__ void stage8(const unsigned short* __restrict__ G,
                                       unsigned short* dst_wave_uniform,
                                       int rowbase, int rl, int p, int kt) {
  // one global_load_lds: 64 lanes x 16B = 8 rows x 128B, linear LDS dest.
  int row = rowbase + rl;
  const unsigned short* src =
      G + (size_t)row * DIM + kt * BK + ((p ^ (row & 7)) << 3);
  __builtin_amdgcn_global_load_lds(
      (const __attribute__((address_space(1))) void*)src,
      (__attribute__((address_space(3))) void*)dst_wave_uniform, 16, 0, 0);
}

__global__ __launch_bounds__(256, 2)
void sim_negsum_kernel(const unsigned short* __restrict__ xb,
                       float* __restrict__ negsum,
                       float* __restrict__ sp_out) {
  const int b = blockIdx.y;
  int ti = 0, rem = blockIdx.x;
  while (rem >= NTILE - ti) { rem -= NTILE - ti; ti++; }
  const int tj = ti + rem;
  const bool diag = (ti == tj);
  const int s0 = ti * BM, t0 = tj * BN;

  __shared__ unsigned short Asm[2][BM * BK];   // 2 x 16 KB
  __shared__ unsigned short Bsm[2][BM * BK];   // 2 x 16 KB

  const unsigned short* Ag = xb + (size_t)b * SEQ * DIM + (size_t)s0 * DIM;
  const unsigned short* Bg = xb + (size_t)b * SEQ * DIM + (size_t)t0 * DIM;

  const int tid  = threadIdx.x;
  const int wid  = tid >> 6;
  const int lane = tid & 63;
  const int wm   = wid >> 1;       // wave row strip (0..1)
  const int wn   = wid & 1;        // wave col strip (0..1)
  const int kg   = lane >> 4;      // k-group 0..3
  const int cl   = lane & 15;
  const int rl   = lane >> 3;      // staging: row-in-group 0..7
  const int p    = lane & 7;       // staging: 16B slot 0..7

  f32x4 acc[4][4];
#pragma unroll
  for (int m = 0; m < 4; ++m)
#pragma unroll
    for (int n = 0; n < 4; ++n)
      acc[m][n] = (f32x4){0.f, 0.f, 0.f, 0.f};

  // ---- staging helper: wave wid stages rows [wid*32, wid*32+32) ----
  // A always; B skipped on diagonal tiles (B-tile == A-tile).
#define STAGE_KT(buf, kt)                                                     \
  do {                                                                        \
    _Pragma("unroll")                                                         \
    for (int it = 0; it < 4; ++it) {                                          \
      int rowbase = wid * 32 + it * 8;                                        \
      stage8(Ag, &Asm[buf][rowbase * BK], rowbase, rl, p, kt);                \
      if (!diag) stage8(Bg, &Bsm[buf][rowbase * BK], rowbase, rl, p, kt);     \
    }                                                                         \
  } while (0)

  const unsigned short* Bsm0 = diag ? &Asm[0][0] : &Bsm[0][0];
  const unsigned short* Bsm1 = diag ? &Asm[1][0] : &Bsm[1][0];

  STAGE_KT(0, 0);
  __syncthreads();

#pragma unroll
  for (int kt = 0; kt < DIM / BK; ++kt) {   // 4 K-steps
    if (kt < 3) {
      if (kt & 1) STAGE_KT(0, kt + 1); else STAGE_KT(1, kt + 1);
    }
    const unsigned short* Acur = &Asm[kt & 1][0];
    const unsigned short* Bcur = (kt & 1) ? Bsm1 : Bsm0;

#pragma unroll
    for (int kk = 0; kk < BK / 32; ++kk) {
      bf16x8 af[4], bfr[4];
#pragma unroll
      for (int m = 0; m < 4; ++m) {
        int r = wm * 64 + m * 16 + cl;
        int slot = kk * 4 + kg;
        af[m] = *reinterpret_cast<const bf16x8*>(
            reinterpret_cast<const char*>(Acur) + r * 128 + ((slot ^ (r & 7)) << 4));
      }
#pragma unroll
      for (int n = 0; n < 4; ++n) {
        int r = wn * 64 + n * 16 + cl;
        int slot = kk * 4 + kg;
        bfr[n] = *reinterpret_cast<const bf16x8*>(
            reinterpret_cast<const char*>(Bcur) + r * 128 + ((slot ^ (r & 7)) << 4));
      }
#pragma unroll
      for (int m = 0; m < 4; ++m)
#pragma unroll
        for (int n = 0; n < 4; ++n)
          acc[m][n] = __builtin_amdgcn_mfma_f32_16x16x32_bf16(
              af[m], bfr[n], acc[m][n], 0, 0, 0);
    }
    __syncthreads();   // drains prefetch vmcnt + protects buffer reuse
  }
#undef STAGE_KT

  // ---- epilogue: exp + mask + row/col partial sums + sp extraction ----
  // C/D layout (HW-verified): col = lane&15, row = (lane>>4)*4 + reg
  float rowpart[4][4];
  float colpart[4];
#pragma unroll
  for (int m = 0; m < 4; ++m)
#pragma unroll
    for (int r = 0; r < 4; ++r) rowpart[m][r] = 0.f;
#pragma unroll
  for (int n = 0; n < 4; ++n) colpart[n] = 0.f;

#pragma unroll
  for (int m = 0; m < 4; ++m) {
#pragma unroll
    for (int n = 0; n < 4; ++n) {
#pragma unroll
      for (int r = 0; r < 4; ++r) {
        int srow = s0 + wm * 64 + m * 16 + (kg << 2) + r;
        int tcol = t0 + wn * 64 + n * 16 + cl;
        int diff = tcol - srow;
        int d = diff < 0 ? -diff : diff;
        float e = (d >= NEGW) ? __expf(acc[m][n][r] * TINV) : 0.f;
        rowpart[m][r] += e;
        colpart[n]    += e;
        if (diff == 1)   // positive pair (srow, srow+1): unique writer
          sp_out[(size_t)b * (SEQ - 1) + srow] = acc[m][n][r] * TINV;
      }
    }
  }

#pragma unroll
  for (int off = 1; off <= 8; off <<= 1)
#pragma unroll
    for (int m = 0; m < 4; ++m)
#pragma unroll
      for (int r = 0; r < 4; ++r)
        rowpart[m][r] += __shfl_xor(rowpart[m][r], off, 64);
  if (cl == 0) {
#pragma unroll
    for (int m = 0; m < 4; ++m)
#pragma unroll
      for (int r = 0; r < 4; ++r)
        atomicAdd(&negsum[(size_t)b * SEQ + s0 + wm * 64 + m * 16 + (kg << 2) + r],
                  rowpart[m][r]);
  }

  if (!diag) {
#pragma unroll
    for (int off = 16; off <= 32; off <<= 1)
#pragma unroll
      for (int n = 0; n < 4; ++n)
        colpart[n] += __shfl_xor(colpart[n], off, 64);
    if (lane < 16) {
#pragma unroll
      for (int n = 0; n < 4; ++n)
        atomicAdd(&negsum[(size_t)b * SEQ + t0 + wn * 64 + n * 16 + lane],
                  colpart[n]);
    }
  }
}

// ---------------------------------------------------------------------------
// Kernel 3: positive-pair loss from precomputed sp (round-4: the adjacent
// dots come out of the Gram tiles; this is now just exp/log + reduce).
// One thread per pair; one atomic per block (64 total).
// ---------------------------------------------------------------------------
__device__ __forceinline__ int negcnt(int s) {
  int a = s - (NEGW - 1);      if (a < 0) a = 0;
  int b = SEQ - NEGW - s;      if (b < 0) b = 0;
  return a + b;
}

__global__ __launch_bounds__(256)
void pos_loss_kernel(const float* __restrict__ sp,
                     const float* __restrict__ negsum,
                     float* __restrict__ loss) {
  __shared__ float red[4];
  const int NP = BATCH * (SEQ - 1);
  int pidx = blockIdx.x * 256 + threadIdx.x;
  float term = 0.f;
  if (pidx < NP) {
    int b = pidx / (SEQ - 1), s = pidx % (SEQ - 1);
    float spv = sp[pidx];
    float e = __expf(spv);
    if (negcnt(s) > 0)     term += logf(e + negsum[(size_t)b * SEQ + s])     - spv;
    if (negcnt(s + 1) > 0) term += logf(e + negsum[(size_t)b * SEQ + s + 1]) - spv;
  }
#pragma unroll
  for (int off = 32; off; off >>= 1) term += __shfl_xor(term, off, 64);
  if ((threadIdx.x & 63) == 0) red[threadIdx.x >> 6] = term;
  __syncthreads();
  if (threadIdx.x == 0)
    atomicAdd(loss, red[0] + red[1] + red[2] + red[3]);
}

// ---------------------------------------------------------------------------
// Kernel 4: finalize — n_valid computed generically, out = loss / n_valid.
// ---------------------------------------------------------------------------
__global__ void finalize_kernel(const float* __restrict__ loss,
                                float* __restrict__ out) {
  int lane = threadIdx.x;   // 64 threads
  int cnt = 0;
  for (int s = lane; s < SEQ; s += 64) {
    if (negcnt(s) > 0) cnt += (s > 0) + (s < SEQ - 1);
  }
#pragma unroll
  for (int off = 32; off; off >>= 1) cnt += __shfl_xor(cnt, off, 64);
  if (lane == 0) {
    long long nv = (long long)BATCH * cnt;
    out[0] = (nv > 0) ? loss[0] / (float)nv : 0.0f;
  }
}

// ---------------------------------------------------------------------------
// Launch. Workspace layout (~8.6 MB):
//   [0, 8388608)              xb: bf16 normalized feats
//   [8388608, +65536)         negsum: fp32 [B][S]        (zeroed by k1)
//   [8454144, +64)            loss accumulator + pad     (zeroed by k1)
//   [8454208, +65504)         sp: fp32 [B][S-1]          (fully overwritten)
// ---------------------------------------------------------------------------
extern "C" void kernel_launch(void* const* d_in, const int* in_sizes, int n_in,
                              void* d_out, int out_size, void* d_ws, size_t ws_size,
                              hipStream_t stream) {
  const float* x = (const float*)d_in[0];
  unsigned short* xb = (unsigned short*)d_ws;
  const size_t XB_BYTES = (size_t)BATCH * SEQ * DIM * 2;   // 8388608
  const size_t NS_BYTES = (size_t)BATCH * SEQ * 4;         // 65536
  float* negsum = (float*)((char*)d_ws + XB_BYTES);
  float* loss   = (float*)((char*)d_ws + XB_BYTES + NS_BYTES);
  float* sp     = (float*)((char*)d_ws + XB_BYTES + NS_BYTES + 64);

  normalize_bf16_kernel<<<(BATCH * SEQ) / 4, 256, 0, stream>>>(x, xb, negsum);

  dim3 g2(NPAIR, BATCH);
  sim_negsum_kernel<<<g2, 256, 0, stream>>>(xb, negsum, sp);

  const int NP = BATCH * (SEQ - 1);
  pos_loss_kernel<<<(NP + 255) / 256, 256, 0, stream>>>(sp, negsum, loss);

  finalize_kernel<<<1, 64, 0, stream>>>(loss, (float*)d_out);
}